// Round 7
// baseline (368.041 us; speedup 1.0000x reference)
//
#include <hip/hip_runtime.h>
#include <cstdint>

#define EPSF 1e-5f
#define SCALEF 0.25f  // D^-0.5

typedef __attribute__((ext_vector_type(8))) __fp16 f16x8;   // 8 fp16 = 4 VGPR
typedef __attribute__((ext_vector_type(2))) __fp16 f16x2;
typedef __attribute__((ext_vector_type(4))) float f32x4;

union U4H8 { uint4 u; f16x8 v; unsigned short s[8]; };

__device__ __forceinline__ uint32_t pk2h(float a, float b){
    union { f16x2 h; uint32_t u; } c;
    c.h = __builtin_amdgcn_cvt_pkrtz(a, b);   // v_cvt_pkrtz_f16_f32
    return c.u;
}
__device__ __forceinline__ void gload_lds16(const void* g, void* l){
    __builtin_amdgcn_global_load_lds((const __attribute__((address_space(1))) uint32_t*)g,
                                     (__attribute__((address_space(3))) uint32_t*)l, 16, 0, 0);
}

// ws layout (bytes):
//   Ft  : f16 [64][128 h][256 k]    @ 0           (4,194,304 B)
//   kv  : f16 [256][8192][16]       @ 4,194,304   (67,108,864 B)
//   q2  : f32 [256][32][16]         @ 71,303,168  (524,288 B)
//   P   : f32 [256][8][32][16]      @ 71,827,456  (4,194,304 B)

// ---------------------------------------------------------------------------
// Kernel 1: fused weight, transposed + fp16 (unchanged).
// ---------------------------------------------------------------------------
__global__ void k_fuseF(const float* __restrict__ wc, const float* __restrict__ E,
                        unsigned short* __restrict__ Ft){
    const int blk = blockIdx.x;
    const int n2 = blk >> 4, x = blk & 15;
    const int h = threadIdx.x;
    const int j = (n2 & 3) * 16 + x;
    float w[16];
#pragma unroll
    for (int t = 0; t < 16; ++t) w[t] = wc[j * 16 + t];
    const float* Eb = E + ((size_t)n2 * 256 + x * 16) * 128 + h;
    float e[16];
#pragma unroll
    for (int t = 0; t < 16; ++t) e[t] = Eb[(size_t)t * 128];
    float v[16];
#pragma unroll
    for (int dd = 0; dd < 16; ++dd){
        const int r = dd >> 2, k = dd & 3;
        float acc = 0.f;
#pragma unroll
        for (int c = 0; c < 4; ++c) acc += w[k * 4 + c] * e[r * 4 + c];
        v[dd] = acc;
    }
    uint32_t pk[8];
#pragma unroll
    for (int q = 0; q < 8; ++q) pk[q] = pk2h(v[q * 2], v[q * 2 + 1]);
    unsigned short* dst = Ft + (size_t)n2 * 32768 + (size_t)h * 256 + x * 16;
    ((uint4*)dst)[0] = make_uint4(pk[0], pk[1], pk[2], pk[3]);
    ((uint4*)dst)[1] = make_uint4(pk[4], pk[5], pk[6], pk[7]);
}

// ---------------------------------------------------------------------------
// Kernel 2: q2 (unchanged).
// ---------------------------------------------------------------------------
__global__ void k_q2(const float* __restrict__ npse, const float* __restrict__ wn,
                     float* __restrict__ q2g){
    const int b = blockIdx.x;
    const int t = threadIdx.x;           // 0..511
    const int o = t >> 4, d = t & 15, r = d >> 2, c = d & 3;
    float acc = 0.f;
#pragma unroll
    for (int k = 0; k < 4; ++k)
        acc += wn[o * 16 + r * 4 + k] * npse[((size_t)b * 32 + o) * 16 + k * 4 + c];
    q2g[(size_t)b * 512 + t] = acc * SCALEF;
}

// ---------------------------------------------------------------------------
// Kernel 3: MFMA GEMM — exact ROUND-4 version (best measured config:
// fp16, DMA-B, double-buffered 2-barrier, __launch_bounds__(256,4)).
// THIS ROUND: launched 4x (idempotent) for timing attribution.
// ---------------------------------------------------------------------------
__global__ __launch_bounds__(256, 4) void k_gemm(const float* __restrict__ cp,
                                                 const unsigned short* __restrict__ Ft,
                                                 unsigned short* __restrict__ kv){
    __shared__ unsigned short As[2][128 * 32];
    __shared__ unsigned short Fs[2][128 * 32];
    const int tid  = threadIdx.x;
    const int lane = tid & 63;
    const int wave = tid >> 6;              // 0..3
    const int wm = wave >> 1, wn = wave & 1;
    const int l15 = lane & 15, g = lane >> 4;
    const int mtile = blockIdx.x;           // 0..31
    const int n2 = blockIdx.y;              // 0..63
    const int n2h = n2 >> 4, y = n2 & 15;

    // ---- A staging map: 4 x float4 per thread per K-step ----
    const float* abase[4];
    int aoff[4];
#pragma unroll
    for (int p = 0; p < 4; ++p){
        const int idx = tid + p * 256;      // 0..1023
        const int m = idx >> 3;             // 0..127
        const int kq = idx & 7;             // k = kq*4
        const int b = mtile * 8 + (m >> 4);
        const int i = (m & 15) * 4 + n2h;
        abase[p] = cp + (size_t)b * 262144 + (size_t)i * 4096 + (size_t)y * 256 + kq * 4;
        aoff[p] = m * 32 + (((kq >> 1) ^ ((m >> 1) & 3)) * 8) + (kq & 1) * 4;
    }
    // ---- B staging: 2 x 16B DMA per thread per K-step, source pre-swizzled ----
    const unsigned short* bsrc[2];
    unsigned short* bdst[2];                // wave-uniform LDS base (lane x16B auto)
#pragma unroll
    for (int p = 0; p < 2; ++p){
        const int idx = tid + p * 256;      // 0..511
        const int h = idx >> 2;             // 0..127
        const int kq4 = idx & 3;            // chunk of 8 f16
        bsrc[p] = Ft + (size_t)n2 * 32768 + (size_t)h * 256 + ((kq4 ^ ((h >> 1) & 3)) * 8);
        bdst[p] = &Fs[0][(size_t)(p * 256 + (tid & ~63)) * 8];
    }
    // ---- fragment read offsets ----
    int afoff[4], bfoff[4];
#pragma unroll
    for (int mf = 0; mf < 4; ++mf){
        const int row = wm * 64 + mf * 16 + l15;
        afoff[mf] = row * 32 + ((g ^ ((row >> 1) & 3)) * 8);
    }
#pragma unroll
    for (int nf = 0; nf < 4; ++nf){
        const int row = wn * 64 + nf * 16 + l15;
        bfoff[nf] = row * 32 + ((g ^ ((row >> 1) & 3)) * 8);
    }

    f32x4 acc[4][4];
#pragma unroll
    for (int mf = 0; mf < 4; ++mf)
#pragma unroll
        for (int nf = 0; nf < 4; ++nf) acc[mf][nf] = (f32x4){0.f, 0.f, 0.f, 0.f};

    float4 av[4];
    const int FBUF = 128 * 32;   // ushorts per Fs buffer
    // ---- prologue: stage kt=0 into buf 0 ----
#pragma unroll
    for (int p = 0; p < 4; ++p) av[p] = *(const float4*)(abase[p]);
#pragma unroll
    for (int p = 0; p < 2; ++p) gload_lds16(bsrc[p], bdst[p]);
#pragma unroll
    for (int p = 0; p < 4; ++p){
        uint2 w2 = make_uint2(pk2h(av[p].x, av[p].y), pk2h(av[p].z, av[p].w));
        *(uint2*)(&As[0][aoff[p]]) = w2;
    }
    __syncthreads();

    for (int kt = 0; kt < 8; ++kt){
        const int cur = kt & 1;
        if (kt < 7){                        // issue next-tile loads early
#pragma unroll
            for (int p = 0; p < 4; ++p) av[p] = *(const float4*)(abase[p] + (kt + 1) * 32);
#pragma unroll
            for (int p = 0; p < 2; ++p)
                gload_lds16(bsrc[p] + (kt + 1) * 32, bdst[p] + (cur ^ 1) * FBUF);
        }
        // compute current buffer
        f16x8 af[4], bfr[4];
#pragma unroll
        for (int mf = 0; mf < 4; ++mf) af[mf] = *(const f16x8*)(&As[cur][afoff[mf]]);
#pragma unroll
        for (int nf = 0; nf < 4; ++nf) bfr[nf] = *(const f16x8*)(&Fs[cur][bfoff[nf]]);
#pragma unroll
        for (int nf = 0; nf < 4; ++nf)
#pragma unroll
            for (int mf = 0; mf < 4; ++mf)
                acc[mf][nf] = __builtin_amdgcn_mfma_f32_16x16x32_f16(af[mf], bfr[nf], acc[mf][nf], 0, 0, 0);
        if (kt < 7){                        // write next A tile into the free buffer
            const int nxt = cur ^ 1;
#pragma unroll
            for (int p = 0; p < 4; ++p){
                uint2 w2 = make_uint2(pk2h(av[p].x, av[p].y), pk2h(av[p].z, av[p].w));
                *(uint2*)(&As[nxt][aoff[p]]) = w2;
            }
        }
        __syncthreads();
    }

    // ---- epilogue: C/D frag (col=lane&15, row=(lane>>4)*4+r); r -> d2 consecutive
#pragma unroll
    for (int mf = 0; mf < 4; ++mf)
#pragma unroll
        for (int nf = 0; nf < 4; ++nf){
            uint2 st = make_uint2(pk2h(acc[mf][nf][0], acc[mf][nf][1]),
                                  pk2h(acc[mf][nf][2], acc[mf][nf][3]));
            const size_t base =
                ((size_t)(mtile * 8 + wm * 4 + mf) * 8192 +
                 (size_t)n2 * 128 + wn * 64 + nf * 16 + l15) * 16 + g * 4;
            *(uint2*)(kv + base) = st;
        }
}

// ---------------------------------------------------------------------------
// Kernel 4: MFMA routing (fp16). Unchanged.
// ---------------------------------------------------------------------------
__global__ __launch_bounds__(256) void k_attn(const unsigned short* __restrict__ kv,
                                              const float* __restrict__ q2g,
                                              float* __restrict__ P){
    __shared__ __align__(16) char smem[47616];   // 4 waves x 11904 B
    const int tid = threadIdx.x;
    const int w = tid >> 6, lane = tid & 63;
    const int l15 = lane & 15, g = lane >> 4;
    const int b = blockIdx.x, sp = blockIdx.y;

    char* wb = smem + w * 11904;
    char* kvA = wb;           // [64 n][80 B]: bytes 0..31 = e0..15, 32..63 = 0
    char* kvT = wb + 5120;    // [16 e][136 B]: n*2
    char* wT  = wb + 7296;    // [32 j][144 B]: n*2

    *(uint4*)(kvA + lane * 80 + 32) = make_uint4(0u, 0u, 0u, 0u);
    *(uint4*)(kvA + lane * 80 + 48) = make_uint4(0u, 0u, 0u, 0u);

    // q2 B-frags in regs: lane holds q2[j=jh*16+l15][e=g*8+i], zero for g>=2
    U4H8 bq[2];
#pragma unroll
    for (int jh = 0; jh < 2; ++jh){
        if (g < 2){
            const float* src = q2g + (size_t)b * 512 + (size_t)(jh * 16 + l15) * 16 + g * 8;
            const float4 a = *(const float4*)src;
            const float4 c = *(const float4*)(src + 4);
            bq[jh].u.x = pk2h(a.x, a.y);
            bq[jh].u.y = pk2h(a.z, a.w);
            bq[jh].u.z = pk2h(c.x, c.y);
            bq[jh].u.w = pk2h(c.z, c.w);
        } else {
            bq[jh].u = make_uint4(0u, 0u, 0u, 0u);
        }
    }

    f32x4 acc[2];
    acc[0] = (f32x4){0.f, 0.f, 0.f, 0.f};
    acc[1] = (f32x4){0.f, 0.f, 0.f, 0.f};
    const f32x4 zf = (f32x4){0.f, 0.f, 0.f, 0.f};

    const int nbase0 = sp * 1024 + w * 256;
    for (int c = 0; c < 4; ++c){
        const int nb = nbase0 + c * 64;
        // ---- stage 64 kv rows ----
#pragma unroll
        for (int p = 0; p < 2; ++p){
            const int idx = p * 64 + lane;
            const int nl = idx >> 1, g2 = idx & 1;
            U4H8 v;
            v.u = *(const uint4*)(kv + ((size_t)b * 8192 + nb + nl) * 16 + g2 * 8);
            *(uint4*)(kvA + nl * 80 + g2 * 16) = v.u;
#pragma unroll
            for (int i = 0; i < 8; ++i)
                *(unsigned short*)(kvT + (g2 * 8 + i) * 136 + nl * 2) = v.s[i];
        }
        // ---- logits + softmax per 16n subtile ----
#pragma unroll
        for (int t = 0; t < 4; ++t){
            const int nt = t * 16;
            U4H8 af;
            af.u = *(const uint4*)(kvA + (nt + l15) * 80 + g * 16);
            f32x4 s0 = __builtin_amdgcn_mfma_f32_16x16x32_f16(af.v, bq[0].v, zf, 0, 0, 0);
            f32x4 s1 = __builtin_amdgcn_mfma_f32_16x16x32_f16(af.v, bq[1].v, zf, 0, 0, 0);
            float e0[4], e1[4], dinv[4];
#pragma unroll
            for (int r = 0; r < 4; ++r){ e0[r] = __expf(s0[r]); e1[r] = __expf(s1[r]); }
#pragma unroll
            for (int r = 0; r < 4; ++r){
                float tmp = e0[r] + e1[r];
                tmp += __shfl_xor(tmp, 1);
                tmp += __shfl_xor(tmp, 2);
                tmp += __shfl_xor(tmp, 4);
                tmp += __shfl_xor(tmp, 8);
                dinv[r] = 1.f / tmp;
            }
#pragma unroll
            for (int r = 0; r < 4; ++r){
                const int ncol = nt + g * 4 + r;
                *(unsigned short*)(wT + (l15)      * 144 + ncol * 2) =
                    (unsigned short)(pk2h(e0[r] * dinv[r], 0.f) & 0xFFFFu);
                *(unsigned short*)(wT + (16 + l15) * 144 + ncol * 2) =
                    (unsigned short)(pk2h(e1[r] * dinv[r], 0.f) & 0xFFFFu);
            }
        }
        // ---- PV: cand[j][e] += sum_n w[j][n] kv[n][e], K=32 x2 ----
#pragma unroll
        for (int kb = 0; kb < 2; ++kb){
            U4H8 pb;
            const uint2 lo = *(const uint2*)(kvT + l15 * 136 + kb * 64 + g * 16);
            const uint2 hi = *(const uint2*)(kvT + l15 * 136 + kb * 64 + g * 16 + 8);
            pb.u = make_uint4(lo.x, lo.y, hi.x, hi.y);
#pragma unroll
            for (int jh = 0; jh < 2; ++jh){
                U4H8 pa;
                pa.u = *(const uint4*)(wT + (jh * 16 + l15) * 144 + kb * 64 + g * 16);
                acc[jh] = __builtin_amdgcn_mfma_f32_16x16x32_f16(pa.v, pb.v, acc[jh], 0, 0, 0);
            }
        }
    }

    // ---- epilogue: per-wave partial [32 j][16 e] into own LDS slice, then block sum
    float* red = (float*)wb;   // aliases kvA (done with it)
#pragma unroll
    for (int jh = 0; jh < 2; ++jh)
#pragma unroll
        for (int r = 0; r < 4; ++r)
            red[(jh * 16 + g * 4 + r) * 16 + l15] = acc[jh][r];
    __syncthreads();
#pragma unroll
    for (int q = 0; q < 2; ++q){
        const int idx = tid + q * 256;   // j*16+e
        float s = 0.f;
#pragma unroll
        for (int ww = 0; ww < 4; ++ww) s += ((float*)(smem + ww * 11904))[idx];
        P[((size_t)b * 8 + sp) * 512 + idx] = s;
    }
}

// ---------------------------------------------------------------------------
// Kernel 5: reduce 8 splits, w_next transform, LayerNorm, store. Unchanged.
// ---------------------------------------------------------------------------
__global__ __launch_bounds__(512) void k_fin(const float* __restrict__ P,
                                             const float* __restrict__ wn,
                                             const float* __restrict__ lnw,
                                             const float* __restrict__ lnb,
                                             float* __restrict__ out){
    __shared__ float cnd[512];
    const int b = blockIdx.x, t = threadIdx.x;
    float s = 0.f;
#pragma unroll
    for (int sp = 0; sp < 8; ++sp) s += P[((size_t)b * 8 + sp) * 512 + t];
    cnd[t] = s;
    __syncthreads();
    if (t < 32){
        const int o = t;
        float m2[16];
#pragma unroll
        for (int r = 0; r < 4; ++r)
#pragma unroll
            for (int c = 0; c < 4; ++c){
                float a = 0.f;
#pragma unroll
                for (int k = 0; k < 4; ++k)
                    a += wn[o * 16 + r * 4 + k] * cnd[o * 16 + k * 4 + c];
                m2[r * 4 + c] = a;
            }
        float mu = 0.f;
#pragma unroll
        for (int e = 0; e < 16; ++e) mu += m2[e];
        mu *= (1.f / 16.f);
        float var = 0.f;
#pragma unroll
        for (int e = 0; e < 16; ++e){ const float d = m2[e] - mu; var += d * d; }
        var *= (1.f / 16.f);
        const float invs = rsqrtf(var + EPSF);
#pragma unroll
        for (int e = 0; e < 16; ++e)
            out[(size_t)b * 512 + o * 16 + e] = (m2[e] - mu) * invs * lnw[e] + lnb[e];
    }
}

// ---------------------------------------------------------------------------
// DIAGNOSTIC ROUND: k_gemm launched 4x (idempotent — writes identical kv).
// gemm_time = (dur_us - 134.9) / 3.
// ---------------------------------------------------------------------------
extern "C" void kernel_launch(void* const* d_in, const int* in_sizes, int n_in,
                              void* d_out, int out_size, void* d_ws, size_t ws_size,
                              hipStream_t stream){
    const float* cp   = (const float*)d_in[0];   // current_pose [256][64][16][16][16]
    const float* npse = (const float*)d_in[1];   // next_pose    [256][32][16]
    const float* wc   = (const float*)d_in[2];   // w_current    [64][4][4]
    const float* wn   = (const float*)d_in[3];   // w_next       [32][4][4]
    const float* E    = (const float*)d_in[4];   // E_proj       [64][256][128]
    const float* lnw  = (const float*)d_in[5];   // ln_weight    [16]
    const float* lnb  = (const float*)d_in[6];   // ln_bias      [16]
    float* out = (float*)d_out;

    char* ws = (char*)d_ws;
    unsigned short* Ft  = (unsigned short*)ws;                         // 4,194,304 B
    unsigned short* kvb = (unsigned short*)(ws + 4194304);             // 67,108,864 B
    float*          q2g = (float*)(ws + 71303168);                     // 524,288 B
    float*          Pp  = (float*)(ws + 71827456);                     // 4,194,304 B

    hipLaunchKernelGGL(k_fuseF, dim3(1024), dim3(128), 0, stream, wc, E, Ft);
    hipLaunchKernelGGL(k_q2,    dim3(256),  dim3(512), 0, stream, npse, wn, q2g);
    hipLaunchKernelGGL(k_gemm,  dim3(32, 64), dim3(256), 0, stream, cp, Ft, kvb);
    hipLaunchKernelGGL(k_gemm,  dim3(32, 64), dim3(256), 0, stream, cp, Ft, kvb);
    hipLaunchKernelGGL(k_gemm,  dim3(32, 64), dim3(256), 0, stream, cp, Ft, kvb);
    hipLaunchKernelGGL(k_gemm,  dim3(32, 64), dim3(256), 0, stream, cp, Ft, kvb);
    hipLaunchKernelGGL(k_attn,  dim3(256, 8), dim3(256), 0, stream, kvb, q2g, Pp);
    hipLaunchKernelGGL(k_fin,   dim3(256),  dim3(512), 0, stream, Pp, wn, lnw, lnb, out);
}

// Round 10
// 118.682 us; speedup vs baseline: 3.1011x; 3.1011x over previous
//
#include <hip/hip_runtime.h>
#include <cstdint>

#define EPSF 1e-5f
#define SCALEF 0.25f  // D^-0.5

typedef __attribute__((ext_vector_type(8))) __fp16 f16x8;   // 8 fp16 = 4 VGPR
typedef __attribute__((ext_vector_type(2))) __fp16 f16x2;
typedef __attribute__((ext_vector_type(4))) float f32x4;

union U4H8 { uint4 u; f16x8 v; unsigned short s[8]; };

__device__ __forceinline__ uint32_t pk2h(float a, float b){
    union { f16x2 h; uint32_t u; } c;
    c.h = __builtin_amdgcn_cvt_pkrtz(a, b);   // v_cvt_pkrtz_f16_f32
    return c.u;
}
__device__ __forceinline__ void gload_lds16(const void* g, void* l){
    __builtin_amdgcn_global_load_lds((const __attribute__((address_space(1))) uint32_t*)g,
                                     (__attribute__((address_space(3))) uint32_t*)l, 16, 0, 0);
}

// ws layout (bytes) — 76,021,760 total (r1-proven footprint):
//   Ft  : f16 [64][128 h][256 k]    @ 0           (4,194,304 B)
//   kv  : f16 [256][8192][16]       @ 4,194,304   (67,108,864 B)
//   q2  : f32 [256][32][16]         @ 71,303,168  (524,288 B)
//   P   : f32 [256][8][32][16]      @ 71,827,456  (4,194,304 B)

// ---------------------------------------------------------------------------
// Kernel 1: fused weight, transposed + fp16 (unchanged).
// ---------------------------------------------------------------------------
__global__ void k_fuseF(const float* __restrict__ wc, const float* __restrict__ E,
                        unsigned short* __restrict__ Ft){
    const int blk = blockIdx.x;
    const int n2 = blk >> 4, x = blk & 15;
    const int h = threadIdx.x;
    const int j = (n2 & 3) * 16 + x;
    float w[16];
#pragma unroll
    for (int t = 0; t < 16; ++t) w[t] = wc[j * 16 + t];
    const float* Eb = E + ((size_t)n2 * 256 + x * 16) * 128 + h;
    float e[16];
#pragma unroll
    for (int t = 0; t < 16; ++t) e[t] = Eb[(size_t)t * 128];
    float v[16];
#pragma unroll
    for (int dd = 0; dd < 16; ++dd){
        const int r = dd >> 2, k = dd & 3;
        float acc = 0.f;
#pragma unroll
        for (int c = 0; c < 4; ++c) acc += w[k * 4 + c] * e[r * 4 + c];
        v[dd] = acc;
    }
    uint32_t pk[8];
#pragma unroll
    for (int q = 0; q < 8; ++q) pk[q] = pk2h(v[q * 2], v[q * 2 + 1]);
    unsigned short* dst = Ft + (size_t)n2 * 32768 + (size_t)h * 256 + x * 16;
    ((uint4*)dst)[0] = make_uint4(pk[0], pk[1], pk[2], pk[3]);
    ((uint4*)dst)[1] = make_uint4(pk[4], pk[5], pk[6], pk[7]);
}

// ---------------------------------------------------------------------------
// Kernel 2: q2 (unchanged).
// ---------------------------------------------------------------------------
__global__ void k_q2(const float* __restrict__ npse, const float* __restrict__ wn,
                     float* __restrict__ q2g){
    const int b = blockIdx.x;
    const int t = threadIdx.x;           // 0..511
    const int o = t >> 4, d = t & 15, r = d >> 2, c = d & 3;
    float acc = 0.f;
#pragma unroll
    for (int k = 0; k < 4; ++k)
        acc += wn[o * 16 + r * 4 + k] * npse[((size_t)b * 32 + o) * 16 + k * 4 + c];
    q2g[(size_t)b * 512 + t] = acc * SCALEF;
}

// ---------------------------------------------------------------------------
// Kernel 3: MFMA GEMM — exact round-4 version (measured: 77.7 us).
// ---------------------------------------------------------------------------
__global__ __launch_bounds__(256, 4) void k_gemm(const float* __restrict__ cp,
                                                 const unsigned short* __restrict__ Ft,
                                                 unsigned short* __restrict__ kv){
    __shared__ unsigned short As[2][128 * 32];
    __shared__ unsigned short Fs[2][128 * 32];
    const int tid  = threadIdx.x;
    const int lane = tid & 63;
    const int wave = tid >> 6;              // 0..3
    const int wm = wave >> 1, wn = wave & 1;
    const int l15 = lane & 15, g = lane >> 4;
    const int mtile = blockIdx.x;           // 0..31
    const int n2 = blockIdx.y;              // 0..63
    const int n2h = n2 >> 4, y = n2 & 15;

    const float* abase[4];
    int aoff[4];
#pragma unroll
    for (int p = 0; p < 4; ++p){
        const int idx = tid + p * 256;      // 0..1023
        const int m = idx >> 3;             // 0..127
        const int kq = idx & 7;             // k = kq*4
        const int b = mtile * 8 + (m >> 4);
        const int i = (m & 15) * 4 + n2h;
        abase[p] = cp + (size_t)b * 262144 + (size_t)i * 4096 + (size_t)y * 256 + kq * 4;
        aoff[p] = m * 32 + (((kq >> 1) ^ ((m >> 1) & 3)) * 8) + (kq & 1) * 4;
    }
    const unsigned short* bsrc[2];
    unsigned short* bdst[2];                // wave-uniform LDS base (lane x16B auto)
#pragma unroll
    for (int p = 0; p < 2; ++p){
        const int idx = tid + p * 256;      // 0..511
        const int h = idx >> 2;             // 0..127
        const int kq4 = idx & 3;            // chunk of 8 f16
        bsrc[p] = Ft + (size_t)n2 * 32768 + (size_t)h * 256 + ((kq4 ^ ((h >> 1) & 3)) * 8);
        bdst[p] = &Fs[0][(size_t)(p * 256 + (tid & ~63)) * 8];
    }
    int afoff[4], bfoff[4];
#pragma unroll
    for (int mf = 0; mf < 4; ++mf){
        const int row = wm * 64 + mf * 16 + l15;
        afoff[mf] = row * 32 + ((g ^ ((row >> 1) & 3)) * 8);
    }
#pragma unroll
    for (int nf = 0; nf < 4; ++nf){
        const int row = wn * 64 + nf * 16 + l15;
        bfoff[nf] = row * 32 + ((g ^ ((row >> 1) & 3)) * 8);
    }

    f32x4 acc[4][4];
#pragma unroll
    for (int mf = 0; mf < 4; ++mf)
#pragma unroll
        for (int nf = 0; nf < 4; ++nf) acc[mf][nf] = (f32x4){0.f, 0.f, 0.f, 0.f};

    float4 av[4];
    const int FBUF = 128 * 32;   // ushorts per Fs buffer
#pragma unroll
    for (int p = 0; p < 4; ++p) av[p] = *(const float4*)(abase[p]);
#pragma unroll
    for (int p = 0; p < 2; ++p) gload_lds16(bsrc[p], bdst[p]);
#pragma unroll
    for (int p = 0; p < 4; ++p){
        uint2 w2 = make_uint2(pk2h(av[p].x, av[p].y), pk2h(av[p].z, av[p].w));
        *(uint2*)(&As[0][aoff[p]]) = w2;
    }
    __syncthreads();

    for (int kt = 0; kt < 8; ++kt){
        const int cur = kt & 1;
        if (kt < 7){
#pragma unroll
            for (int p = 0; p < 4; ++p) av[p] = *(const float4*)(abase[p] + (kt + 1) * 32);
#pragma unroll
            for (int p = 0; p < 2; ++p)
                gload_lds16(bsrc[p] + (kt + 1) * 32, bdst[p] + (cur ^ 1) * FBUF);
        }
        f16x8 af[4], bfr[4];
#pragma unroll
        for (int mf = 0; mf < 4; ++mf) af[mf] = *(const f16x8*)(&As[cur][afoff[mf]]);
#pragma unroll
        for (int nf = 0; nf < 4; ++nf) bfr[nf] = *(const f16x8*)(&Fs[cur][bfoff[nf]]);
#pragma unroll
        for (int nf = 0; nf < 4; ++nf)
#pragma unroll
            for (int mf = 0; mf < 4; ++mf)
                acc[mf][nf] = __builtin_amdgcn_mfma_f32_16x16x32_f16(af[mf], bfr[nf], acc[mf][nf], 0, 0, 0);
        if (kt < 7){
            const int nxt = cur ^ 1;
#pragma unroll
            for (int p = 0; p < 4; ++p){
                uint2 w2 = make_uint2(pk2h(av[p].x, av[p].y), pk2h(av[p].z, av[p].w));
                *(uint2*)(&As[nxt][aoff[p]]) = w2;
            }
        }
        __syncthreads();
    }

#pragma unroll
    for (int mf = 0; mf < 4; ++mf)
#pragma unroll
        for (int nf = 0; nf < 4; ++nf){
            uint2 st = make_uint2(pk2h(acc[mf][nf][0], acc[mf][nf][1]),
                                  pk2h(acc[mf][nf][2], acc[mf][nf][3]));
            const size_t base =
                ((size_t)(mtile * 8 + wm * 4 + mf) * 8192 +
                 (size_t)n2 * 128 + wn * 64 + nf * 16 + l15) * 16 + g * 4;
            *(uint2*)(kv + base) = st;
        }
}

// ---------------------------------------------------------------------------
// Kernel 4: MFMA routing. Swapped logits (A=q2, B=kv) + j-major w store +
// e-major kvT, all via plain swizzled ds ops (NO tr_read).
// grid (256 b, 8 sp), 256 thr = 4 indep waves; wave: 256 n in 4 chunks of 64.
// Per-wave LDS (9216 B): kvA [64n][48B] | kvT [16e][128B swz] | wJ [32j][128B swz]
// swizzle: byte_in_row ^= (row&7)<<4  (16B-aligned preserving, bijective).
// ---------------------------------------------------------------------------
__global__ __launch_bounds__(256) void k_attn(const unsigned short* __restrict__ kv,
                                              const float* __restrict__ q2g,
                                              float* __restrict__ P){
    __shared__ __align__(16) char smem[4 * 9216];
    const int tid = threadIdx.x;
    const int w = tid >> 6, lane = tid & 63;
    const int l15 = lane & 15, g = lane >> 4;
    const int b = blockIdx.x, sp = blockIdx.y;

    char* wb  = smem + w * 9216;
    char* kvA = wb;            // [64 n][48 B] (e f16 at bytes 0..31; 32..47 pad)
    char* kvT = wb + 3072;     // [16 e][128 B] col n*2 ^ ((e&7)<<4)
    char* wJ  = wb + 5120;     // [32 j][128 B] col n*2 ^ ((j&7)<<4)

    // q2 A-frags: lane l15 = j-row, k-slots e = 8g+i (zero for g>=2)
    U4H8 aq[2];
#pragma unroll
    for (int jh = 0; jh < 2; ++jh){
        if (g < 2){
            const float* src = q2g + (size_t)b * 512 + (size_t)(jh * 16 + l15) * 16 + g * 8;
            const float4 a = *(const float4*)src;
            const float4 c = *(const float4*)(src + 4);
            aq[jh].u.x = pk2h(a.x, a.y);
            aq[jh].u.y = pk2h(a.z, a.w);
            aq[jh].u.z = pk2h(c.x, c.y);
            aq[jh].u.w = pk2h(c.z, c.w);
        } else {
            aq[jh].u = make_uint4(0u, 0u, 0u, 0u);
        }
    }

    f32x4 acc[2];
    acc[0] = (f32x4){0.f, 0.f, 0.f, 0.f};
    acc[1] = (f32x4){0.f, 0.f, 0.f, 0.f};
    const f32x4 zf = (f32x4){0.f, 0.f, 0.f, 0.f};

    const int nbase0 = sp * 1024 + w * 256;
    for (int c = 0; c < 4; ++c){
        const int nb = nbase0 + c * 64;
        // ---- stage: lane owns row n=lane; p = e-block ----
#pragma unroll
        for (int p = 0; p < 2; ++p){
            U4H8 v;
            v.u = *(const uint4*)(kv + ((size_t)b * 8192 + nb + lane) * 16 + p * 8);
            *(uint4*)(kvA + lane * 48 + p * 16) = v.u;
#pragma unroll
            for (int i = 0; i < 8; ++i){
                const int e = p * 8 + i;
                *(unsigned short*)(kvT + e * 128 + ((lane * 2) ^ ((e & 7) << 4))) = v.s[i];
            }
        }
        // ---- logits (swapped) + softmax + wJ writes per 16-n subtile ----
#pragma unroll
        for (int t = 0; t < 4; ++t){
            U4H8 bk;   // B-frag: col n = t*16+l15; k-slots e (g>=2 dup'd, A=0 there)
            bk.u = *(const uint4*)(kvA + (t * 16 + l15) * 48 + (g & 1) * 16);
            f32x4 s0 = __builtin_amdgcn_mfma_f32_16x16x32_f16(aq[0].v, bk.v, zf, 0, 0, 0);
            f32x4 s1 = __builtin_amdgcn_mfma_f32_16x16x32_f16(aq[1].v, bk.v, zf, 0, 0, 0);
            float e0[4], e1[4];
#pragma unroll
            for (int r = 0; r < 4; ++r){ e0[r] = __expf(s0[r]); e1[r] = __expf(s1[r]); }
            float ts = ((e0[0] + e0[1]) + (e0[2] + e0[3])) + ((e1[0] + e1[1]) + (e1[2] + e1[3]));
            ts += __shfl_xor(ts, 16);
            ts += __shfl_xor(ts, 32);
            const float dinv = 1.f / ts;
            const int ncol2 = (t * 16 + l15) * 2;
#pragma unroll
            for (int r = 0; r < 4; ++r){
                const int j0 = 4 * g + r;
                const int sw = (j0 & 7) << 4;           // (16+j0)&7 == j0&7
                *(unsigned short*)(wJ + j0 * 128 + (ncol2 ^ sw)) =
                    (unsigned short)(pk2h(e0[r] * dinv, 0.f) & 0xFFFFu);
                *(unsigned short*)(wJ + (16 + j0) * 128 + (ncol2 ^ sw)) =
                    (unsigned short)(pk2h(e1[r] * dinv, 0.f) & 0xFFFFu);
            }
        }
        // ---- PV: acc[j][e] += sum_n w[j][n] kv[n][e], two K=32 MFMAs ----
#pragma unroll
        for (int kb = 0; kb < 2; ++kb){
            const int cb = kb * 64 + g * 16;            // col-bytes: n = kb*32+8g+i
            const int swl = (l15 & 7) << 4;
            U4H8 A0, A1, B;
            A0.u = *(const uint4*)(wJ + l15 * 128 + (cb ^ swl));          // w[j=l15][n]
            A1.u = *(const uint4*)(wJ + (16 + l15) * 128 + (cb ^ swl));   // w[j=16+l15][n]
            B.u  = *(const uint4*)(kvT + l15 * 128 + (cb ^ swl));         // kv[n][e=l15]
            acc[0] = __builtin_amdgcn_mfma_f32_16x16x32_f16(A0.v, B.v, acc[0], 0, 0, 0);
            acc[1] = __builtin_amdgcn_mfma_f32_16x16x32_f16(A1.v, B.v, acc[1], 0, 0, 0);
        }
    }

    // ---- epilogue: per-wave partial [32 j][16 e] into own slice, block sum ----
    float* red = (float*)wb;   // aliases kvA region (2 KB needed, 3 KB available)
#pragma unroll
    for (int jh = 0; jh < 2; ++jh)
#pragma unroll
        for (int r = 0; r < 4; ++r)
            red[(jh * 16 + g * 4 + r) * 16 + l15] = acc[jh][r];
    __syncthreads();
#pragma unroll
    for (int q = 0; q < 2; ++q){
        const int idx = tid + q * 256;   // j*16+e
        float s = 0.f;
#pragma unroll
        for (int ww = 0; ww < 4; ++ww) s += ((float*)(smem + ww * 9216))[idx];
        P[((size_t)b * 8 + sp) * 512 + idx] = s;
    }
}

// ---------------------------------------------------------------------------
// Kernel 5: reduce 8 splits, w_next transform, LayerNorm, store.
// ---------------------------------------------------------------------------
__global__ __launch_bounds__(512) void k_fin(const float* __restrict__ P,
                                             const float* __restrict__ wn,
                                             const float* __restrict__ lnw,
                                             const float* __restrict__ lnb,
                                             float* __restrict__ out){
    __shared__ float cnd[512];
    const int b = blockIdx.x, t = threadIdx.x;
    float s = 0.f;
#pragma unroll
    for (int sp = 0; sp < 8; ++sp) s += P[((size_t)b * 8 + sp) * 512 + t];
    cnd[t] = s;
    __syncthreads();
    if (t < 32){
        const int o = t;
        float m2[16];
#pragma unroll
        for (int r = 0; r < 4; ++r)
#pragma unroll
            for (int c = 0; c < 4; ++c){
                float a = 0.f;
#pragma unroll
                for (int k = 0; k < 4; ++k)
                    a += wn[o * 16 + r * 4 + k] * cnd[o * 16 + k * 4 + c];
                m2[r * 4 + c] = a;
            }
        float mu = 0.f;
#pragma unroll
        for (int e = 0; e < 16; ++e) mu += m2[e];
        mu *= (1.f / 16.f);
        float var = 0.f;
#pragma unroll
        for (int e = 0; e < 16; ++e){ const float d = m2[e] - mu; var += d * d; }
        var *= (1.f / 16.f);
        const float invs = rsqrtf(var + EPSF);
#pragma unroll
        for (int e = 0; e < 16; ++e)
            out[(size_t)b * 512 + o * 16 + e] = (m2[e] - mu) * invs * lnw[e] + lnb[e];
    }
}

// ---------------------------------------------------------------------------
extern "C" void kernel_launch(void* const* d_in, const int* in_sizes, int n_in,
                              void* d_out, int out_size, void* d_ws, size_t ws_size,
                              hipStream_t stream){
    const float* cp   = (const float*)d_in[0];   // current_pose [256][64][16][16][16]
    const float* npse = (const float*)d_in[1];   // next_pose    [256][32][16]
    const float* wc   = (const float*)d_in[2];   // w_current    [64][4][4]
    const float* wn   = (const float*)d_in[3];   // w_next       [32][4][4]
    const float* E    = (const float*)d_in[4];   // E_proj       [64][256][128]
    const float* lnw  = (const float*)d_in[5];   // ln_weight    [16]
    const float* lnb  = (const float*)d_in[6];   // ln_bias      [16]
    float* out = (float*)d_out;

    char* ws = (char*)d_ws;
    unsigned short* Ft  = (unsigned short*)ws;                         // 4,194,304 B
    unsigned short* kvb = (unsigned short*)(ws + 4194304);             // 67,108,864 B
    float*          q2g = (float*)(ws + 71303168);                     // 524,288 B
    float*          Pp  = (float*)(ws + 71827456);                     // 4,194,304 B

    hipLaunchKernelGGL(k_fuseF, dim3(1024), dim3(128), 0, stream, wc, E, Ft);
    hipLaunchKernelGGL(k_q2,    dim3(256),  dim3(512), 0, stream, npse, wn, q2g);
    hipLaunchKernelGGL(k_gemm,  dim3(32, 64), dim3(256), 0, stream, cp, Ft, kvb);
    hipLaunchKernelGGL(k_attn,  dim3(256, 8), dim3(256), 0, stream, kvb, q2g, Pp);
    hipLaunchKernelGGL(k_fin,   dim3(256),  dim3(512), 0, stream, Pp, wn, lnw, lnb, out);
}